// Round 10
// baseline (237.003 us; speedup 1.0000x reference)
//
#include <hip/hip_runtime.h>

#define NEV    1000000
#define POUT   4096
#define PIN    16384
#define INV2PI 0.15915494309189535f

typedef __bf16 bf16x8 __attribute__((ext_vector_type(8)));
typedef float  f32x16 __attribute__((ext_vector_type(16)));

#define FT_FLOATS (32 * PIN)

#define LH_ST 36   // u32 stride: 144B rows -> 16B-aligned, 4-bank rotation per row
#define LW_ST 36

#define SEL_HI 0x07060302u   // perm(a,b,SEL_HI) = [hi16(a) | hi16(b)]
#define SEL_LO 0x05040100u

// pack f32 v into u32: bf16_trunc(v) in high 16, bf16_trunc(v - trunc(v)) in low 16
__device__ __forceinline__ unsigned pack_hl(float v) {
    const unsigned b = __builtin_bit_cast(unsigned, v);
    const float hb = __builtin_bit_cast(float, b & 0xFFFF0000u);
    const float lo = v - hb;
    return __builtin_amdgcn_perm(b, __builtin_bit_cast(unsigned, lo), SEL_HI);
}

// 3-product split-bf16 MFMA: acc += (Ahi+Alo)(Bhi+Blo), dropping Alo*Blo
#define GEMM3(accv, ahi_, alo_, bhi_, blo_)                                          \
    accv = __builtin_amdgcn_mfma_f32_32x32x16_bf16(ahi_, bhi_, accv, 0, 0, 0);       \
    accv = __builtin_amdgcn_mfma_f32_32x32x16_bf16(ahi_, blo_, accv, 0, 0, 0);       \
    accv = __builtin_amdgcn_mfma_f32_32x32x16_bf16(alo_, bhi_, accv, 0, 0, 0);

// featT[p*32 + c] = features[c*PIN + p]  (coalesced tiled transpose)
__global__ __launch_bounds__(256) void prep_k(const float* __restrict__ f,
                                              float* __restrict__ ws) {
    __shared__ float tile[32][33];
    const int t = threadIdx.x;
    const int p0 = blockIdx.x * 32;
    #pragma unroll
    for (int rep = 0; rep < 4; ++rep) {
        const int idx = rep * 256 + t;
        const int c = idx >> 5, pl = idx & 31;
        tile[pl][c] = f[c * PIN + p0 + pl];
    }
    __syncthreads();
    #pragma unroll
    for (int rep = 0; rep < 4; ++rep) {
        const int idx = rep * 256 + t;
        const int pl = idx >> 5, c = idx & 31;
        ws[(p0 + pl) * 32 + c] = tile[pl][c];
    }
}

template <int MODE>   // 0: featT in ws; 2: direct feature gather (fallback)
__global__ __launch_bounds__(64, 3) void quadconv_mfma_k(
    const float* __restrict__ features,
    const float* __restrict__ eval_locs,
    const float* __restrict__ quad_weights,
    const float* __restrict__ W0,
    const float* __restrict__ W1,
    const float* __restrict__ W2,
    const int* __restrict__ eio,
    const int* __restrict__ eii,
    const float* __restrict__ ws,
    float* __restrict__ out)               // (4, 8, 4096)
{
    __shared__ unsigned lh[64 * LH_ST];   // h1 planes: [khid][eval], u32 = hi|lo
    __shared__ unsigned lw[32 * LW_ST];   // wg planes: [bi][eval]
    const int lane = threadIdx.x;
    const int n    = lane & 31;
    const int hl   = lane >> 5;
    const int p    = blockIdx.x;          // this wave's output segment

    // segment bounds: 2-lane parallel lower_bound on sorted eio
    int start, end;
    {
        const int tgt = p + (lane & 1);
        int lo = 0, hi = NEV;
        while (lo < hi) { int m = (lo + hi) >> 1; if (eio[m] < tgt) lo = m + 1; else hi = m; }
        start = __shfl(lo, 0);
        end   = __shfl(lo, 1);
    }

    // ---- resident A-fragments: (W1^T)/2pi (M=64 x K=64), truncation hi/lo split ----
    // A[m][k]: m=(lane&31)+32*mb, k=8*hl+e+16*t -> W1[k*64+m]
    bf16x8 a1hi[2][4], a1lo[2][4];
    #pragma unroll
    for (int mb = 0; mb < 2; ++mb) {
        #pragma unroll
        for (int t = 0; t < 4; ++t) {
            unsigned hw[4], lw_[4];
            #pragma unroll
            for (int i = 0; i < 4; ++i) {
                const float v0 = W1[(8 * hl + 2 * i + 16 * t) * 64 + n + 32 * mb] * INV2PI;
                const float v1 = W1[(8 * hl + 2 * i + 1 + 16 * t) * 64 + n + 32 * mb] * INV2PI;
                const unsigned b0 = __builtin_bit_cast(unsigned, v0);
                const unsigned b1 = __builtin_bit_cast(unsigned, v1);
                const float l0 = v0 - __builtin_bit_cast(float, b0 & 0xFFFF0000u);
                const float l1 = v1 - __builtin_bit_cast(float, b1 & 0xFFFF0000u);
                hw[i]  = __builtin_amdgcn_perm(b1, b0, SEL_HI);
                lw_[i] = __builtin_amdgcn_perm(__builtin_bit_cast(unsigned, l1),
                                               __builtin_bit_cast(unsigned, l0), SEL_HI);
            }
            a1hi[mb][t] = __builtin_bit_cast(bf16x8, make_uint4(hw[0], hw[1], hw[2], hw[3]));
            a1lo[mb][t] = __builtin_bit_cast(bf16x8, make_uint4(lw_[0], lw_[1], lw_[2], lw_[3]));
        }
    }

    // persistent accumulator T[khid, (b,i)] (64x32)
    f32x16 T[2];
    #pragma unroll
    for (int mb = 0; mb < 2; ++mb)
        #pragma unroll
        for (int r = 0; r < 16; ++r) T[mb][r] = 0.f;

    unsigned* Lhw = &lh[4 * hl * LH_ST + n];        // write base (h1)
    unsigned* Lww = &lw[16 * hl * LW_ST + n];       // write base (wg)
    const unsigned* Lhr = &lh[n * LH_ST + 8 * hl];  // read base (GEMM2 A)
    const unsigned* Lwr = &lw[n * LW_ST + 8 * hl];  // read base (GEMM2 B)

    const int nt = (end - start + 31) >> 5;

    for (int tile = 0; tile < nt; ++tile) {
        const int e  = start + tile * 32 + n;
        const bool valid = (e < end);
        const int ec = valid ? e : (end - 1);
        const float2 x = ((const float2*)eval_locs)[ec];
        const int ii = eii[ec];

        const float r2 = x.x * x.x + x.y * x.y;
        const float dd = 1.0f - 1048576.0f * r2 * r2;      // 1 - DECAY*r4 >= 0.33
        float wgt = __expf(1.0f - 1.0f / dd) * quad_weights[ii];
        if (!valid) wgt = 0.f;

        const float xs = x.x * INV2PI;
        const float ys = x.y * INV2PI;

        // ---- GEMM1: (H1pre^T)/2pi = (W1^T/2pi) @ H0^T ; B built in-register ----
        f32x16 acc1[2];
        #pragma unroll
        for (int mb = 0; mb < 2; ++mb)
            #pragma unroll
            for (int r = 0; r < 16; ++r) acc1[mb][r] = 0.f;

        #pragma unroll
        for (int t = 0; t < 4; ++t) {
            const int k0 = 16 * t + 8 * hl;
            float s[8];
            #pragma unroll
            for (int q = 0; q < 8; ++q)    // v_sin: arg in revolutions -> sin(x.W0col)
                s[q] = __builtin_amdgcn_sinf(fmaf(xs, W0[k0 + q], ys * W0[64 + k0 + q]));
            unsigned hw[4], lw_[4];
            #pragma unroll
            for (int i = 0; i < 4; ++i) {
                const unsigned b0 = __builtin_bit_cast(unsigned, s[2 * i]);
                const unsigned b1 = __builtin_bit_cast(unsigned, s[2 * i + 1]);
                const float l0 = s[2 * i]     - __builtin_bit_cast(float, b0 & 0xFFFF0000u);
                const float l1 = s[2 * i + 1] - __builtin_bit_cast(float, b1 & 0xFFFF0000u);
                hw[i]  = __builtin_amdgcn_perm(b1, b0, SEL_HI);
                lw_[i] = __builtin_amdgcn_perm(__builtin_bit_cast(unsigned, l1),
                                               __builtin_bit_cast(unsigned, l0), SEL_HI);
            }
            const bf16x8 bhi = __builtin_bit_cast(bf16x8, make_uint4(hw[0], hw[1], hw[2], hw[3]));
            const bf16x8 blo = __builtin_bit_cast(bf16x8, make_uint4(lw_[0], lw_[1], lw_[2], lw_[3]));
            GEMM3(acc1[0], a1hi[0][t], a1lo[0][t], bhi, blo);
            GEMM3(acc1[1], a1hi[1][t], a1lo[1][t], bhi, blo);
        }

        // ---- h1 = sin(h1pre) via v_sin (acc1 already in revolutions); pack + store ----
        // C layout: col n, row khid = (r&3)+8*(r>>2)+4*hl+32*mb
        #pragma unroll
        for (int mb = 0; mb < 2; ++mb) {
            #pragma unroll
            for (int r = 0; r < 16; ++r) {
                const int row = ((r & 3) + 8 * (r >> 2) + 32 * mb);   // + 4*hl in base
                Lhw[row * LH_ST] = pack_hl(__builtin_amdgcn_sinf(acc1[mb][r]));
            }
        }

        // ---- wg[bi] = wgt * g[bi], bi = 16*hl + v; write plane Lw[bi][e=n] ----
        {
            float g[16];
            if constexpr (MODE == 0) {
                const float4* gp = (const float4*)(ws + ii * 32 + 16 * hl);
                const float4 G0 = gp[0], G1 = gp[1], G2 = gp[2], G3 = gp[3];
                g[0]=G0.x; g[1]=G0.y; g[2]=G0.z; g[3]=G0.w;
                g[4]=G1.x; g[5]=G1.y; g[6]=G1.z; g[7]=G1.w;
                g[8]=G2.x; g[9]=G2.y; g[10]=G2.z; g[11]=G2.w;
                g[12]=G3.x; g[13]=G3.y; g[14]=G3.z; g[15]=G3.w;
            } else {
                #pragma unroll
                for (int v = 0; v < 16; ++v) g[v] = features[(16 * hl + v) * PIN + ii];
            }
            #pragma unroll
            for (int v = 0; v < 16; ++v) Lww[v * LW_ST] = pack_hl(wgt * g[v]);
        }

        // ---- GEMM2': T[khid,(b,i)] += h1(64 x e) @ wg(e x 32) over 32 evals ----
        #pragma unroll
        for (int kt = 0; kt < 2; ++kt) {
            const uint4 p0 = *(const uint4*)(Lwr + 16 * kt);
            const uint4 p1 = *(const uint4*)(Lwr + 16 * kt + 4);
            const bf16x8 bh = __builtin_bit_cast(bf16x8, make_uint4(
                __builtin_amdgcn_perm(p0.y, p0.x, SEL_HI),
                __builtin_amdgcn_perm(p0.w, p0.z, SEL_HI),
                __builtin_amdgcn_perm(p1.y, p1.x, SEL_HI),
                __builtin_amdgcn_perm(p1.w, p1.z, SEL_HI)));
            const bf16x8 bl = __builtin_bit_cast(bf16x8, make_uint4(
                __builtin_amdgcn_perm(p0.y, p0.x, SEL_LO),
                __builtin_amdgcn_perm(p0.w, p0.z, SEL_LO),
                __builtin_amdgcn_perm(p1.y, p1.x, SEL_LO),
                __builtin_amdgcn_perm(p1.w, p1.z, SEL_LO)));
            #pragma unroll
            for (int mb = 0; mb < 2; ++mb) {
                const uint4 q0 = *(const uint4*)(Lhr + 32 * mb * LH_ST + 16 * kt);
                const uint4 q1 = *(const uint4*)(Lhr + 32 * mb * LH_ST + 16 * kt + 4);
                const bf16x8 ah = __builtin_bit_cast(bf16x8, make_uint4(
                    __builtin_amdgcn_perm(q0.y, q0.x, SEL_HI),
                    __builtin_amdgcn_perm(q0.w, q0.z, SEL_HI),
                    __builtin_amdgcn_perm(q1.y, q1.x, SEL_HI),
                    __builtin_amdgcn_perm(q1.w, q1.z, SEL_HI)));
                const bf16x8 al = __builtin_bit_cast(bf16x8, make_uint4(
                    __builtin_amdgcn_perm(q0.y, q0.x, SEL_LO),
                    __builtin_amdgcn_perm(q0.w, q0.z, SEL_LO),
                    __builtin_amdgcn_perm(q1.y, q1.x, SEL_LO),
                    __builtin_amdgcn_perm(q1.w, q1.z, SEL_LO)));
                GEMM3(T[mb], ah, al, bh, bl);
            }
        }
    }

    // ---- epilogue: out[b,j] = sum_{khid,i} W2[khid][i*8+j] * T[khid][b*8+i] ----
    {
        const int i = n & 7, b = n >> 3;
        float pj[8];
        #pragma unroll
        for (int j = 0; j < 8; ++j) pj[j] = 0.f;
        #pragma unroll
        for (int mb = 0; mb < 2; ++mb) {
            #pragma unroll
            for (int r = 0; r < 16; ++r) {
                const int khid = (r & 3) + 8 * (r >> 2) + 4 * hl + 32 * mb;
                const float tv = T[mb][r];
                const float4 w20 = *(const float4*)(W2 + khid * 64 + i * 8);
                const float4 w21 = *(const float4*)(W2 + khid * 64 + i * 8 + 4);
                pj[0] = fmaf(tv, w20.x, pj[0]);
                pj[1] = fmaf(tv, w20.y, pj[1]);
                pj[2] = fmaf(tv, w20.z, pj[2]);
                pj[3] = fmaf(tv, w20.w, pj[3]);
                pj[4] = fmaf(tv, w21.x, pj[4]);
                pj[5] = fmaf(tv, w21.y, pj[5]);
                pj[6] = fmaf(tv, w21.z, pj[6]);
                pj[7] = fmaf(tv, w21.w, pj[7]);
            }
        }
        #pragma unroll
        for (int j = 0; j < 8; ++j) {   // reduce over i (xor 1,2,4) and hl (xor 32)
            float v = pj[j];
            v += __shfl_xor(v, 1);
            v += __shfl_xor(v, 2);
            v += __shfl_xor(v, 4);
            v += __shfl_xor(v, 32);
            pj[j] = v;
        }
        if (i == 0 && hl == 0) {
            #pragma unroll
            for (int j = 0; j < 8; ++j) out[b * (8 * POUT) + j * POUT + p] = pj[j];
        }
    }
}

extern "C" void kernel_launch(void* const* d_in, const int* in_sizes, int n_in,
                              void* d_out, int out_size, void* d_ws, size_t ws_size,
                              hipStream_t stream) {
    const float* features  = (const float*)d_in[0];
    const float* eval_locs = (const float*)d_in[1];
    const float* qw        = (const float*)d_in[2];
    const float* W0        = (const float*)d_in[3];
    const float* W1        = (const float*)d_in[4];
    const float* W2        = (const float*)d_in[5];
    const int*   eio       = (const int*)d_in[6];
    const int*   eii       = (const int*)d_in[7];
    float* out = (float*)d_out;
    float* ws  = (float*)d_ws;

    if (ws_size >= (size_t)FT_FLOATS * 4) {
        prep_k<<<PIN / 32, 256, 0, stream>>>(features, ws);
        quadconv_mfma_k<0><<<POUT, 64, 0, stream>>>(features, eval_locs, qw, W0, W1, W2,
                                                    eio, eii, ws, out);
    } else {
        quadconv_mfma_k<2><<<POUT, 64, 0, stream>>>(features, eval_locs, qw, W0, W1, W2,
                                                    eio, eii, ws, out);
    }
}

// Round 11
// 152.949 us; speedup vs baseline: 1.5496x; 1.5496x over previous
//
#include <hip/hip_runtime.h>

#define NEV    1000000
#define POUT   4096
#define PIN    16384
#define INV2PI 0.15915494309189535f

typedef __bf16 bf16x8 __attribute__((ext_vector_type(8)));
typedef float  f32x16 __attribute__((ext_vector_type(16)));

#define FT_FLOATS (32 * PIN)

#define LH_ST 36   // u32 stride: 144B rows -> 16B-aligned, 4-bank rotation per row
#define LW_ST 36

#define SEL_HI 0x07060302u   // perm(a,b,SEL_HI) = [hi16(a) | hi16(b)]
#define SEL_LO 0x05040100u

// pack f32 v into u32: bf16_trunc(v) in high 16, bf16_trunc(v - trunc(v)) in low 16
__device__ __forceinline__ unsigned pack_hl(float v) {
    const unsigned b = __builtin_bit_cast(unsigned, v);
    const float hb = __builtin_bit_cast(float, b & 0xFFFF0000u);
    const float lo = v - hb;
    return __builtin_amdgcn_perm(b, __builtin_bit_cast(unsigned, lo), SEL_HI);
}

// 3-product split-bf16 MFMA: acc += (Ahi+Alo)(Bhi+Blo), dropping Alo*Blo
#define GEMM3(accv, ahi_, alo_, bhi_, blo_)                                          \
    accv = __builtin_amdgcn_mfma_f32_32x32x16_bf16(ahi_, bhi_, accv, 0, 0, 0);       \
    accv = __builtin_amdgcn_mfma_f32_32x32x16_bf16(ahi_, blo_, accv, 0, 0, 0);       \
    accv = __builtin_amdgcn_mfma_f32_32x32x16_bf16(alo_, bhi_, accv, 0, 0, 0);

// featT[p*32 + c] = features[c*PIN + p]  (coalesced tiled transpose)
__global__ __launch_bounds__(256) void prep_k(const float* __restrict__ f,
                                              float* __restrict__ ws) {
    __shared__ float tile[32][33];
    const int t = threadIdx.x;
    const int p0 = blockIdx.x * 32;
    #pragma unroll
    for (int rep = 0; rep < 4; ++rep) {
        const int idx = rep * 256 + t;
        const int c = idx >> 5, pl = idx & 31;
        tile[pl][c] = f[c * PIN + p0 + pl];
    }
    __syncthreads();
    #pragma unroll
    for (int rep = 0; rep < 4; ++rep) {
        const int idx = rep * 256 + t;
        const int pl = idx >> 5, c = idx & 31;
        ws[(p0 + pl) * 32 + c] = tile[pl][c];
    }
}

template <int MODE>   // 0: featT in ws; 2: direct feature gather (fallback)
__global__ __launch_bounds__(64, 2) void quadconv_mfma_k(
    const float* __restrict__ features,
    const float* __restrict__ eval_locs,
    const float* __restrict__ quad_weights,
    const float* __restrict__ W0,
    const float* __restrict__ W1,
    const float* __restrict__ W2,
    const int* __restrict__ eio,
    const int* __restrict__ eii,
    const float* __restrict__ ws,
    float* __restrict__ out)               // (4, 8, 4096)
{
    __shared__ unsigned lh[64 * LH_ST];   // h1 planes: [khid][eval], u32 = hi|lo
    __shared__ unsigned lw[32 * LW_ST];   // wg planes: [bi][eval]
    const int lane = threadIdx.x;
    const int n    = lane & 31;
    const int hl   = lane >> 5;
    const int p    = blockIdx.x;          // this wave's output segment

    // segment bounds: 2-lane parallel lower_bound on sorted eio
    int start, end;
    {
        const int tgt = p + (lane & 1);
        int lo = 0, hi = NEV;
        while (lo < hi) { int m = (lo + hi) >> 1; if (eio[m] < tgt) lo = m + 1; else hi = m; }
        start = __shfl(lo, 0);
        end   = __shfl(lo, 1);
    }

    // ---- resident A-fragments: (W1^T)/2pi (M=64 x K=64), truncation hi/lo split ----
    // A[m][k]: m=(lane&31)+32*mb, k=8*hl+e+16*t -> W1[k*64+m]
    bf16x8 a1hi[2][4], a1lo[2][4];
    #pragma unroll
    for (int mb = 0; mb < 2; ++mb) {
        #pragma unroll
        for (int t = 0; t < 4; ++t) {
            unsigned hw[4], lw_[4];
            #pragma unroll
            for (int i = 0; i < 4; ++i) {
                const float v0 = W1[(8 * hl + 2 * i + 16 * t) * 64 + n + 32 * mb] * INV2PI;
                const float v1 = W1[(8 * hl + 2 * i + 1 + 16 * t) * 64 + n + 32 * mb] * INV2PI;
                const unsigned b0 = __builtin_bit_cast(unsigned, v0);
                const unsigned b1 = __builtin_bit_cast(unsigned, v1);
                const float l0 = v0 - __builtin_bit_cast(float, b0 & 0xFFFF0000u);
                const float l1 = v1 - __builtin_bit_cast(float, b1 & 0xFFFF0000u);
                hw[i]  = __builtin_amdgcn_perm(b1, b0, SEL_HI);
                lw_[i] = __builtin_amdgcn_perm(__builtin_bit_cast(unsigned, l1),
                                               __builtin_bit_cast(unsigned, l0), SEL_HI);
            }
            a1hi[mb][t] = __builtin_bit_cast(bf16x8, make_uint4(hw[0], hw[1], hw[2], hw[3]));
            a1lo[mb][t] = __builtin_bit_cast(bf16x8, make_uint4(lw_[0], lw_[1], lw_[2], lw_[3]));
        }
    }

    // persistent accumulator T[khid, (b,i)] (64x32)
    f32x16 T[2];
    #pragma unroll
    for (int mb = 0; mb < 2; ++mb)
        #pragma unroll
        for (int r = 0; r < 16; ++r) T[mb][r] = 0.f;

    unsigned* Lhw = &lh[4 * hl * LH_ST + n];        // write base (h1)
    unsigned* Lww = &lw[16 * hl * LW_ST + n];       // write base (wg)
    const unsigned* Lhr = &lh[n * LH_ST + 8 * hl];  // read base (GEMM2 A)
    const unsigned* Lwr = &lw[n * LW_ST + 8 * hl];  // read base (GEMM2 B)

    const int nt = (end - start + 31) >> 5;

    for (int tile = 0; tile < nt; ++tile) {
        const int e  = start + tile * 32 + n;
        const bool valid = (e < end);
        const int ec = valid ? e : (end - 1);
        const float2 x = ((const float2*)eval_locs)[ec];
        const int ii = eii[ec];

        const float r2 = x.x * x.x + x.y * x.y;
        const float dd = 1.0f - 1048576.0f * r2 * r2;      // 1 - DECAY*r4 >= 0.33
        float wgt = __expf(1.0f - 1.0f / dd) * quad_weights[ii];
        if (!valid) wgt = 0.f;

        const float xs = x.x * INV2PI;
        const float ys = x.y * INV2PI;

        // ---- GEMM1: (H1pre^T)/2pi = (W1^T/2pi) @ H0^T ; B built in-register ----
        f32x16 acc1[2];
        #pragma unroll
        for (int mb = 0; mb < 2; ++mb)
            #pragma unroll
            for (int r = 0; r < 16; ++r) acc1[mb][r] = 0.f;

        #pragma unroll
        for (int t = 0; t < 4; ++t) {
            const int k0 = 16 * t + 8 * hl;
            float s[8];
            #pragma unroll
            for (int q = 0; q < 8; ++q)    // v_sin: arg in revolutions -> sin(x.W0col)
                s[q] = __builtin_amdgcn_sinf(fmaf(xs, W0[k0 + q], ys * W0[64 + k0 + q]));
            unsigned hw[4], lw_[4];
            #pragma unroll
            for (int i = 0; i < 4; ++i) {
                const unsigned b0 = __builtin_bit_cast(unsigned, s[2 * i]);
                const unsigned b1 = __builtin_bit_cast(unsigned, s[2 * i + 1]);
                const float l0 = s[2 * i]     - __builtin_bit_cast(float, b0 & 0xFFFF0000u);
                const float l1 = s[2 * i + 1] - __builtin_bit_cast(float, b1 & 0xFFFF0000u);
                hw[i]  = __builtin_amdgcn_perm(b1, b0, SEL_HI);
                lw_[i] = __builtin_amdgcn_perm(__builtin_bit_cast(unsigned, l1),
                                               __builtin_bit_cast(unsigned, l0), SEL_HI);
            }
            const bf16x8 bhi = __builtin_bit_cast(bf16x8, make_uint4(hw[0], hw[1], hw[2], hw[3]));
            const bf16x8 blo = __builtin_bit_cast(bf16x8, make_uint4(lw_[0], lw_[1], lw_[2], lw_[3]));
            GEMM3(acc1[0], a1hi[0][t], a1lo[0][t], bhi, blo);
            GEMM3(acc1[1], a1hi[1][t], a1lo[1][t], bhi, blo);
        }

        // ---- h1 = sin(h1pre) via v_sin (acc1 already in revolutions); pack + store ----
        // C layout: col n, row khid = (r&3)+8*(r>>2)+4*hl+32*mb
        #pragma unroll
        for (int mb = 0; mb < 2; ++mb) {
            #pragma unroll
            for (int r = 0; r < 16; ++r) {
                const int row = ((r & 3) + 8 * (r >> 2) + 32 * mb);   // + 4*hl in base
                Lhw[row * LH_ST] = pack_hl(__builtin_amdgcn_sinf(acc1[mb][r]));
            }
        }

        // ---- wg[bi] = wgt * g[bi], bi = 16*hl + v; write plane Lw[bi][e=n] ----
        {
            float g[16];
            if constexpr (MODE == 0) {
                const float4* gp = (const float4*)(ws + ii * 32 + 16 * hl);
                const float4 G0 = gp[0], G1 = gp[1], G2 = gp[2], G3 = gp[3];
                g[0]=G0.x; g[1]=G0.y; g[2]=G0.z; g[3]=G0.w;
                g[4]=G1.x; g[5]=G1.y; g[6]=G1.z; g[7]=G1.w;
                g[8]=G2.x; g[9]=G2.y; g[10]=G2.z; g[11]=G2.w;
                g[12]=G3.x; g[13]=G3.y; g[14]=G3.z; g[15]=G3.w;
            } else {
                #pragma unroll
                for (int v = 0; v < 16; ++v) g[v] = features[(16 * hl + v) * PIN + ii];
            }
            #pragma unroll
            for (int v = 0; v < 16; ++v) Lww[v * LW_ST] = pack_hl(wgt * g[v]);
        }

        // ---- GEMM2': T[khid,(b,i)] += h1(64 x e) @ wg(e x 32) over 32 evals ----
        #pragma unroll
        for (int kt = 0; kt < 2; ++kt) {
            const uint4 p0 = *(const uint4*)(Lwr + 16 * kt);
            const uint4 p1 = *(const uint4*)(Lwr + 16 * kt + 4);
            const bf16x8 bh = __builtin_bit_cast(bf16x8, make_uint4(
                __builtin_amdgcn_perm(p0.y, p0.x, SEL_HI),
                __builtin_amdgcn_perm(p0.w, p0.z, SEL_HI),
                __builtin_amdgcn_perm(p1.y, p1.x, SEL_HI),
                __builtin_amdgcn_perm(p1.w, p1.z, SEL_HI)));
            const bf16x8 bl = __builtin_bit_cast(bf16x8, make_uint4(
                __builtin_amdgcn_perm(p0.y, p0.x, SEL_LO),
                __builtin_amdgcn_perm(p0.w, p0.z, SEL_LO),
                __builtin_amdgcn_perm(p1.y, p1.x, SEL_LO),
                __builtin_amdgcn_perm(p1.w, p1.z, SEL_LO)));
            #pragma unroll
            for (int mb = 0; mb < 2; ++mb) {
                const uint4 q0 = *(const uint4*)(Lhr + 32 * mb * LH_ST + 16 * kt);
                const uint4 q1 = *(const uint4*)(Lhr + 32 * mb * LH_ST + 16 * kt + 4);
                const bf16x8 ah = __builtin_bit_cast(bf16x8, make_uint4(
                    __builtin_amdgcn_perm(q0.y, q0.x, SEL_HI),
                    __builtin_amdgcn_perm(q0.w, q0.z, SEL_HI),
                    __builtin_amdgcn_perm(q1.y, q1.x, SEL_HI),
                    __builtin_amdgcn_perm(q1.w, q1.z, SEL_HI)));
                const bf16x8 al = __builtin_bit_cast(bf16x8, make_uint4(
                    __builtin_amdgcn_perm(q0.y, q0.x, SEL_LO),
                    __builtin_amdgcn_perm(q0.w, q0.z, SEL_LO),
                    __builtin_amdgcn_perm(q1.y, q1.x, SEL_LO),
                    __builtin_amdgcn_perm(q1.w, q1.z, SEL_LO)));
                GEMM3(T[mb], ah, al, bh, bl);
            }
        }
    }

    // ---- epilogue: out[b,j] = sum_{khid,i} W2[khid][i*8+j] * T[khid][b*8+i] ----
    {
        const int i = n & 7, b = n >> 3;
        float pj[8];
        #pragma unroll
        for (int j = 0; j < 8; ++j) pj[j] = 0.f;
        #pragma unroll
        for (int mb = 0; mb < 2; ++mb) {
            #pragma unroll
            for (int r = 0; r < 16; ++r) {
                const int khid = (r & 3) + 8 * (r >> 2) + 4 * hl + 32 * mb;
                const float tv = T[mb][r];
                const float4 w20 = *(const float4*)(W2 + khid * 64 + i * 8);
                const float4 w21 = *(const float4*)(W2 + khid * 64 + i * 8 + 4);
                pj[0] = fmaf(tv, w20.x, pj[0]);
                pj[1] = fmaf(tv, w20.y, pj[1]);
                pj[2] = fmaf(tv, w20.z, pj[2]);
                pj[3] = fmaf(tv, w20.w, pj[3]);
                pj[4] = fmaf(tv, w21.x, pj[4]);
                pj[5] = fmaf(tv, w21.y, pj[5]);
                pj[6] = fmaf(tv, w21.z, pj[6]);
                pj[7] = fmaf(tv, w21.w, pj[7]);
            }
        }
        #pragma unroll
        for (int j = 0; j < 8; ++j) {   // reduce over i (xor 1,2,4) and hl (xor 32)
            float v = pj[j];
            v += __shfl_xor(v, 1);
            v += __shfl_xor(v, 2);
            v += __shfl_xor(v, 4);
            v += __shfl_xor(v, 32);
            pj[j] = v;
        }
        if (i == 0 && hl == 0) {
            #pragma unroll
            for (int j = 0; j < 8; ++j) out[b * (8 * POUT) + j * POUT + p] = pj[j];
        }
    }
}

extern "C" void kernel_launch(void* const* d_in, const int* in_sizes, int n_in,
                              void* d_out, int out_size, void* d_ws, size_t ws_size,
                              hipStream_t stream) {
    const float* features  = (const float*)d_in[0];
    const float* eval_locs = (const float*)d_in[1];
    const float* qw        = (const float*)d_in[2];
    const float* W0        = (const float*)d_in[3];
    const float* W1        = (const float*)d_in[4];
    const float* W2        = (const float*)d_in[5];
    const int*   eio       = (const int*)d_in[6];
    const int*   eii       = (const int*)d_in[7];
    float* out = (float*)d_out;
    float* ws  = (float*)d_ws;

    if (ws_size >= (size_t)FT_FLOATS * 4) {
        prep_k<<<PIN / 32, 256, 0, stream>>>(features, ws);
        quadconv_mfma_k<0><<<POUT, 64, 0, stream>>>(features, eval_locs, qw, W0, W1, W2,
                                                    eio, eii, ws, out);
    } else {
        quadconv_mfma_k<2><<<POUT, 64, 0, stream>>>(features, eval_locs, qw, W0, W1, W2,
                                                    eio, eii, ws, out);
    }
}

// Round 12
// 136.279 us; speedup vs baseline: 1.7391x; 1.1223x over previous
//
#include <hip/hip_runtime.h>

#define NEV    1000000
#define POUT   4096
#define PIN    16384
#define INV2PI 0.15915494309189535f

typedef __bf16 bf16x8 __attribute__((ext_vector_type(8)));
typedef float  f32x16 __attribute__((ext_vector_type(16)));

#define SEG_OFF   0
#define FT_OFF    4160
#define FT_FLOATS (32 * PIN)

#define LW_ST 36

#define SEL_HI 0x07060302u   // perm(a,b,SEL_HI) = [hi16(a) | hi16(b)]
#define SEL_LO 0x05040100u

// pack f32 v into u32: bf16_trunc(v) in high 16, bf16_trunc(v - trunc(v)) in low 16
__device__ __forceinline__ unsigned pack_hl(float v) {
    const unsigned b = __builtin_bit_cast(unsigned, v);
    const float hb = __builtin_bit_cast(float, b & 0xFFFF0000u);
    const float lo = v - hb;
    return __builtin_amdgcn_perm(b, __builtin_bit_cast(unsigned, lo), SEL_HI);
}

// 3-product split-bf16 MFMA: acc += (Ahi+Alo)(Bhi+Blo), dropping Alo*Blo
#define GEMM3(accv, ahi_, alo_, bhi_, blo_)                                          \
    accv = __builtin_amdgcn_mfma_f32_32x32x16_bf16(ahi_, bhi_, accv, 0, 0, 0);       \
    accv = __builtin_amdgcn_mfma_f32_32x32x16_bf16(ahi_, blo_, accv, 0, 0, 0);       \
    accv = __builtin_amdgcn_mfma_f32_32x32x16_bf16(alo_, bhi_, accv, 0, 0, 0);

// in-place half-wave swap: a.hi_lanes <-> b.lo_lanes
//   post: a = {a.lo, b.lo},  b = {a.hi, b.hi}
#define PLSWAP(a_, b_) asm("v_permlane32_swap_b32 %0, %1" : "+v"(a_), "+v"(b_))

__global__ __launch_bounds__(256) void prep_k(const float* __restrict__ f,
                                              const int* __restrict__ eio,
                                              float* __restrict__ ws) {
    const int bid = blockIdx.x, t = threadIdx.x;
    if (bid < 512) {                     // coalesced featT transpose: 32 p-rows/block
        __shared__ float tile[32][33];
        const int p0 = bid * 32;
        #pragma unroll
        for (int rep = 0; rep < 4; ++rep) {
            const int idx = rep * 256 + t;
            const int c = idx >> 5, pl = idx & 31;
            tile[pl][c] = f[c * PIN + p0 + pl];
        }
        __syncthreads();
        #pragma unroll
        for (int rep = 0; rep < 4; ++rep) {
            const int idx = rep * 256 + t;
            const int pl = idx >> 5, c = idx & 31;
            ws[FT_OFF + (p0 + pl) * 32 + c] = tile[pl][c];
        }
    } else {                             // seg[q] = lower_bound(eio, q)
        int* seg = (int*)ws + SEG_OFF;
        const int q = (bid - 512) * 256 + t;     // 0..4095
        int lo = 0, hi = NEV;
        while (lo < hi) { int m = (lo + hi) >> 1; if (eio[m] < q) lo = m + 1; else hi = m; }
        seg[q] = lo;
        if (q == 0) seg[POUT] = NEV;
    }
}

template <int MODE>   // 0: seg+featT in ws; 2: no ws (fallback)
__global__ __launch_bounds__(64, 2) void quadconv_mfma_k(
    const float* __restrict__ features,
    const float* __restrict__ eval_locs,
    const float* __restrict__ quad_weights,
    const float* __restrict__ W0,
    const float* __restrict__ W1,
    const float* __restrict__ W2,
    const int* __restrict__ eio,
    const int* __restrict__ eii,
    const float* __restrict__ ws,
    float* __restrict__ out)               // (4, 8, 4096)
{
    __shared__ unsigned lw[32 * LW_ST];   // wg planes: [bi][eval], u32 = hi|lo
    const int lane = threadIdx.x;
    const int n    = lane & 31;
    const int hl   = lane >> 5;
    const int p    = blockIdx.x;          // this wave's output segment

    int start, end;
    if constexpr (MODE == 0) {
        const int* seg = (const int*)ws + SEG_OFF;
        start = seg[p]; end = seg[p + 1];
    } else {
        const int tgt = p + (lane & 1);
        int lo = 0, hi = NEV;
        while (lo < hi) { int m = (lo + hi) >> 1; if (eio[m] < tgt) lo = m + 1; else hi = m; }
        start = __shfl(lo, 0);
        end   = __shfl(lo, 1);
    }

    // ---- resident B-fragments: W1/2pi as B[k=hid0][n=khid], truncation hi/lo split ----
    // B[k][n]: n = (lane&31) + 32*cb, k = 8*hl + e + 16*kt4 -> W1[k*64 + n+32cb]
    bf16x8 b1hi[2][4], b1lo[2][4];
    #pragma unroll
    for (int cb = 0; cb < 2; ++cb) {
        #pragma unroll
        for (int t = 0; t < 4; ++t) {
            unsigned hw[4], lw_[4];
            #pragma unroll
            for (int i = 0; i < 4; ++i) {
                const float v0 = W1[(8 * hl + 2 * i + 16 * t) * 64 + n + 32 * cb] * INV2PI;
                const float v1 = W1[(8 * hl + 2 * i + 1 + 16 * t) * 64 + n + 32 * cb] * INV2PI;
                const unsigned b0 = __builtin_bit_cast(unsigned, v0);
                const unsigned b1 = __builtin_bit_cast(unsigned, v1);
                const float l0 = v0 - __builtin_bit_cast(float, b0 & 0xFFFF0000u);
                const float l1 = v1 - __builtin_bit_cast(float, b1 & 0xFFFF0000u);
                hw[i]  = __builtin_amdgcn_perm(b1, b0, SEL_HI);
                lw_[i] = __builtin_amdgcn_perm(__builtin_bit_cast(unsigned, l1),
                                               __builtin_bit_cast(unsigned, l0), SEL_HI);
            }
            b1hi[cb][t] = __builtin_bit_cast(bf16x8, make_uint4(hw[0], hw[1], hw[2], hw[3]));
            b1lo[cb][t] = __builtin_bit_cast(bf16x8, make_uint4(lw_[0], lw_[1], lw_[2], lw_[3]));
        }
    }

    // persistent accumulator T[khid, (b,i)] (64x32): col n = bi, rows khid
    f32x16 T[2];
    #pragma unroll
    for (int mb = 0; mb < 2; ++mb)
        #pragma unroll
        for (int r = 0; r < 16; ++r) T[mb][r] = 0.f;

    unsigned* Lww = &lw[16 * hl * LW_ST + n];       // write base (wg)
    const unsigned* Lwr = &lw[n * LW_ST + 8 * hl];  // read base (GEMM2 B)

    const int nt = (end - start + 31) >> 5;

    for (int tile = 0; tile < nt; ++tile) {
        const int e  = start + tile * 32 + n;
        const bool valid = (e < end);
        const int ec = valid ? e : (end - 1);
        const float2 x = ((const float2*)eval_locs)[ec];
        const int ii = eii[ec];

        const float r2 = x.x * x.x + x.y * x.y;
        const float dd = 1.0f - 1048576.0f * r2 * r2;      // 1 - DECAY*r4 >= 0.33
        float wgt = __expf(1.0f - 1.0f / dd) * quad_weights[ii];
        if (!valid) wgt = 0.f;

        const float xs = x.x * INV2PI;
        const float ys = x.y * INV2PI;

        // ---- GEMM1 (swapped): C'[eval][khid] = H0 @ (W1/2pi); A = in-register sins ----
        f32x16 acc1[2];
        #pragma unroll
        for (int cb = 0; cb < 2; ++cb)
            #pragma unroll
            for (int r = 0; r < 16; ++r) acc1[cb][r] = 0.f;

        #pragma unroll
        for (int t = 0; t < 4; ++t) {
            const int k0 = 16 * t + 8 * hl;
            float s[8];
            #pragma unroll
            for (int q = 0; q < 8; ++q)    // v_sin: arg in revolutions -> sin(x.W0col)
                s[q] = __builtin_amdgcn_sinf(fmaf(xs, W0[k0 + q], ys * W0[64 + k0 + q]));
            unsigned hw[4], lw_[4];
            #pragma unroll
            for (int i = 0; i < 4; ++i) {
                const unsigned b0 = __builtin_bit_cast(unsigned, s[2 * i]);
                const unsigned b1 = __builtin_bit_cast(unsigned, s[2 * i + 1]);
                const float l0 = s[2 * i]     - __builtin_bit_cast(float, b0 & 0xFFFF0000u);
                const float l1 = s[2 * i + 1] - __builtin_bit_cast(float, b1 & 0xFFFF0000u);
                hw[i]  = __builtin_amdgcn_perm(b1, b0, SEL_HI);
                lw_[i] = __builtin_amdgcn_perm(__builtin_bit_cast(unsigned, l1),
                                               __builtin_bit_cast(unsigned, l0), SEL_HI);
            }
            const bf16x8 ahi = __builtin_bit_cast(bf16x8, make_uint4(hw[0], hw[1], hw[2], hw[3]));
            const bf16x8 alo = __builtin_bit_cast(bf16x8, make_uint4(lw_[0], lw_[1], lw_[2], lw_[3]));
            GEMM3(acc1[0], ahi, alo, b1hi[0][t], b1lo[0][t]);
            GEMM3(acc1[1], ahi, alo, b1hi[1][t], b1lo[1][t]);
        }

        // ---- h1 = v_sin(C') (revolutions), pack hi|lo u32 in-register ----
        // C' lane layout: col khid = n+32cb, row eval = (r&3)+8*(r>>2)+4*hl
        unsigned Q0[16], Q1[16];
        #pragma unroll
        for (int r = 0; r < 16; ++r) Q0[r] = pack_hl(__builtin_amdgcn_sinf(acc1[0][r]));
        #pragma unroll
        for (int r = 0; r < 16; ++r) Q1[r] = pack_hl(__builtin_amdgcn_sinf(acc1[1][r]));

        // ---- wg[bi] = wgt * g[bi], bi = 16*hl + v; LDS plane Lw[bi][eval=n] ----
        {
            float g[16];
            if constexpr (MODE == 0) {
                const float4* gp = (const float4*)(ws + FT_OFF + ii * 32 + 16 * hl);
                const float4 G0 = gp[0], G1 = gp[1], G2 = gp[2], G3 = gp[3];
                g[0]=G0.x; g[1]=G0.y; g[2]=G0.z; g[3]=G0.w;
                g[4]=G1.x; g[5]=G1.y; g[6]=G1.z; g[7]=G1.w;
                g[8]=G2.x; g[9]=G2.y; g[10]=G2.z; g[11]=G2.w;
                g[12]=G3.x; g[13]=G3.y; g[14]=G3.z; g[15]=G3.w;
            } else {
                #pragma unroll
                for (int v = 0; v < 16; ++v) g[v] = features[(16 * hl + v) * PIN + ii];
            }
            #pragma unroll
            for (int v = 0; v < 16; ++v) Lww[v * LW_ST] = pack_hl(wgt * g[v]);
        }

        // ---- redistribute h1 rows across half-waves: A-frags for GEMM2 ----
        // swap(Q[base+j], Q[base+4+j]): Q[base+j] -> elem e=j, Q[base+4+j] -> elem e=4+j
        #pragma unroll
        for (int kt = 0; kt < 2; ++kt) {
            #pragma unroll
            for (int j = 0; j < 4; ++j) { PLSWAP(Q0[8 * kt + j], Q0[8 * kt + 4 + j]); }
            #pragma unroll
            for (int j = 0; j < 4; ++j) { PLSWAP(Q1[8 * kt + j], Q1[8 * kt + 4 + j]); }
        }

        // ---- GEMM2: T[khid][bi] += h1(khid x eval) @ wg(eval x bi), K = 32 evals ----
        #pragma unroll
        for (int kt = 0; kt < 2; ++kt) {
            const uint4 p0 = *(const uint4*)(Lwr + 16 * kt);
            const uint4 p1 = *(const uint4*)(Lwr + 16 * kt + 4);
            const bf16x8 bh = __builtin_bit_cast(bf16x8, make_uint4(
                __builtin_amdgcn_perm(p0.y, p0.x, SEL_HI),
                __builtin_amdgcn_perm(p0.w, p0.z, SEL_HI),
                __builtin_amdgcn_perm(p1.y, p1.x, SEL_HI),
                __builtin_amdgcn_perm(p1.w, p1.z, SEL_HI)));
            const bf16x8 bl = __builtin_bit_cast(bf16x8, make_uint4(
                __builtin_amdgcn_perm(p0.y, p0.x, SEL_LO),
                __builtin_amdgcn_perm(p0.w, p0.z, SEL_LO),
                __builtin_amdgcn_perm(p1.y, p1.x, SEL_LO),
                __builtin_amdgcn_perm(p1.w, p1.z, SEL_LO)));
            {   // mb = 0 : A elems e from Q0[8kt + e']
                const bf16x8 ah = __builtin_bit_cast(bf16x8, make_uint4(
                    __builtin_amdgcn_perm(Q0[8*kt+1], Q0[8*kt+0], SEL_HI),
                    __builtin_amdgcn_perm(Q0[8*kt+3], Q0[8*kt+2], SEL_HI),
                    __builtin_amdgcn_perm(Q0[8*kt+5], Q0[8*kt+4], SEL_HI),
                    __builtin_amdgcn_perm(Q0[8*kt+7], Q0[8*kt+6], SEL_HI)));
                const bf16x8 al = __builtin_bit_cast(bf16x8, make_uint4(
                    __builtin_amdgcn_perm(Q0[8*kt+1], Q0[8*kt+0], SEL_LO),
                    __builtin_amdgcn_perm(Q0[8*kt+3], Q0[8*kt+2], SEL_LO),
                    __builtin_amdgcn_perm(Q0[8*kt+5], Q0[8*kt+4], SEL_LO),
                    __builtin_amdgcn_perm(Q0[8*kt+7], Q0[8*kt+6], SEL_LO)));
                GEMM3(T[0], ah, al, bh, bl);
            }
            {   // mb = 1
                const bf16x8 ah = __builtin_bit_cast(bf16x8, make_uint4(
                    __builtin_amdgcn_perm(Q1[8*kt+1], Q1[8*kt+0], SEL_HI),
                    __builtin_amdgcn_perm(Q1[8*kt+3], Q1[8*kt+2], SEL_HI),
                    __builtin_amdgcn_perm(Q1[8*kt+5], Q1[8*kt+4], SEL_HI),
                    __builtin_amdgcn_perm(Q1[8*kt+7], Q1[8*kt+6], SEL_HI)));
                const bf16x8 al = __builtin_bit_cast(bf16x8, make_uint4(
                    __builtin_amdgcn_perm(Q1[8*kt+1], Q1[8*kt+0], SEL_LO),
                    __builtin_amdgcn_perm(Q1[8*kt+3], Q1[8*kt+2], SEL_LO),
                    __builtin_amdgcn_perm(Q1[8*kt+5], Q1[8*kt+4], SEL_LO),
                    __builtin_amdgcn_perm(Q1[8*kt+7], Q1[8*kt+6], SEL_LO)));
                GEMM3(T[1], ah, al, bh, bl);
            }
        }
    }

    // ---- epilogue: out[b,j] = sum_{khid,i} W2[khid][i*8+j] * T[khid][b*8+i] ----
    {
        const int i = n & 7, b = n >> 3;
        float pj[8];
        #pragma unroll
        for (int j = 0; j < 8; ++j) pj[j] = 0.f;
        #pragma unroll
        for (int mb = 0; mb < 2; ++mb) {
            #pragma unroll
            for (int r = 0; r < 16; ++r) {
                const int khid = (r & 3) + 8 * (r >> 2) + 4 * hl + 32 * mb;
                const float tv = T[mb][r];
                const float4 w20 = *(const float4*)(W2 + khid * 64 + i * 8);
                const float4 w21 = *(const float4*)(W2 + khid * 64 + i * 8 + 4);
                pj[0] = fmaf(tv, w20.x, pj[0]);
                pj[1] = fmaf(tv, w20.y, pj[1]);
                pj[2] = fmaf(tv, w20.z, pj[2]);
                pj[3] = fmaf(tv, w20.w, pj[3]);
                pj[4] = fmaf(tv, w21.x, pj[4]);
                pj[5] = fmaf(tv, w21.y, pj[5]);
                pj[6] = fmaf(tv, w21.z, pj[6]);
                pj[7] = fmaf(tv, w21.w, pj[7]);
            }
        }
        #pragma unroll
        for (int j = 0; j < 8; ++j) {   // reduce over i (xor 1,2,4) and hl (xor 32)
            float v = pj[j];
            v += __shfl_xor(v, 1);
            v += __shfl_xor(v, 2);
            v += __shfl_xor(v, 4);
            v += __shfl_xor(v, 32);
            pj[j] = v;
        }
        if (i == 0 && hl == 0) {
            #pragma unroll
            for (int j = 0; j < 8; ++j) out[b * (8 * POUT) + j * POUT + p] = pj[j];
        }
    }
}

extern "C" void kernel_launch(void* const* d_in, const int* in_sizes, int n_in,
                              void* d_out, int out_size, void* d_ws, size_t ws_size,
                              hipStream_t stream) {
    const float* features  = (const float*)d_in[0];
    const float* eval_locs = (const float*)d_in[1];
    const float* qw        = (const float*)d_in[2];
    const float* W0        = (const float*)d_in[3];
    const float* W1        = (const float*)d_in[4];
    const float* W2        = (const float*)d_in[5];
    const int*   eio       = (const int*)d_in[6];
    const int*   eii       = (const int*)d_in[7];
    float* out = (float*)d_out;
    float* ws  = (float*)d_ws;

    if (ws_size >= (size_t)(FT_OFF + FT_FLOATS) * 4) {
        prep_k<<<512 + POUT / 256, 256, 0, stream>>>(features, eio, ws);
        quadconv_mfma_k<0><<<POUT, 64, 0, stream>>>(features, eval_locs, qw, W0, W1, W2,
                                                    eio, eii, ws, out);
    } else {
        quadconv_mfma_k<2><<<POUT, 64, 0, stream>>>(features, eval_locs, qw, W0, W1, W2,
                                                    eio, eii, ws, out);
    }
}